// Round 8
// baseline (479.344 us; speedup 1.0000x reference)
//
#include <hip/hip_runtime.h>
#include <hip/hip_cooperative_groups.h>

namespace cg = cooperative_groups;

// GraphSAGE 2-layer. N=50000, E=800000, 128 -> 256 -> 256.
// Round 8: one cooperative kernel (k_csr) replaces prep+hist+scan1+scan3f+
// bucket (9 -> 5 dispatches); bucket phase is ILP-4 with line-padded cursors
// and nontemporal epk stores. Gathers/MFMA unchanged from round 7.

#define NN 50000
#define NE 800000
#define CSR_B 256
#define CSR_T 1024
#define CSR_TH (CSR_B * CSR_T)  // 262144
#define NB 49  // ceil(50000/1024) scan chunks

typedef __bf16 v8bf __attribute__((ext_vector_type(8)));
typedef float v4f __attribute__((ext_vector_type(4)));
typedef float nf4 __attribute__((ext_vector_type(4)));
typedef unsigned nu2 __attribute__((ext_vector_type(2)));
typedef int ni2 __attribute__((ext_vector_type(2)));

__device__ __forceinline__ unsigned short f2b(float f) {
    unsigned u = __float_as_uint(f);
    return (unsigned short)((u + 0x7FFFu + ((u >> 16) & 1u)) >> 16);
}
__device__ __forceinline__ float b2f(unsigned short h) {
    return __uint_as_float(((unsigned)h) << 16);
}
__device__ __forceinline__ unsigned pack2(float a, float b) {
    return (unsigned)f2b(a) | ((unsigned)f2b(b) << 16);
}

// Cooperative CSR+prep kernel. Phases separated by grid sync:
//  P0: zero cnt | Bt0 cast | Bt1 cast | x->bf16
//  P1: histogram of dst
//  P2a: per-chunk scan (49 chunks of 1024) -> pre, bsum, dinv
//  P2b: chunk offsets (wave-scan of bsum) -> rp + padded cursor
//  P3: bucket edges into epk (ILP-4, padded-cursor atomics, NT stores)
__global__ __launch_bounds__(CSR_T) void k_csr(const float* __restrict__ x,
                                               const float* __restrict__ Wl0,
                                               const float* __restrict__ Wr0,
                                               const float* __restrict__ Wl1,
                                               const float* __restrict__ Wr1,
                                               const int* __restrict__ src,
                                               const int* __restrict__ dst,
                                               const float* __restrict__ ew,
                                               int* __restrict__ cnt,
                                               int* __restrict__ pre,
                                               int* __restrict__ bsum,
                                               int* __restrict__ rp,
                                               int* __restrict__ curp,   // stride-16 padded
                                               float* __restrict__ dinv,
                                               ni2* __restrict__ epk,
                                               unsigned short* __restrict__ Bt0,
                                               unsigned short* __restrict__ Bt1,
                                               unsigned short* __restrict__ xb) {
    cg::grid_group grid = cg::this_grid();
    const int tid = threadIdx.x;
    const int b = blockIdx.x;
    const int gtid = b * CSR_T + tid;

    // ---- P0: prep ----
    for (int i = gtid; i < NN; i += CSR_TH) cnt[i] = 0;
    for (int idx = gtid; idx < 256 * 256; idx += CSR_TH) {
        int n = idx >> 8, k = idx & 255;
        float v = (k < 128) ? Wl0[(size_t)k * 256 + n] : Wr0[(size_t)(k - 128) * 256 + n];
        Bt0[idx] = f2b(v);
    }
    for (int idx = gtid; idx < 256 * 512; idx += CSR_TH) {
        int n = idx >> 9, k = idx & 511;
        float v = (k < 256) ? Wl1[(size_t)k * 256 + n] : Wr1[(size_t)(k - 256) * 256 + n];
        Bt1[idx] = f2b(v);
    }
    for (int i4 = gtid; i4 < NN * 128 / 4; i4 += CSR_TH) {
        nf4 v = __builtin_nontemporal_load((const nf4*)x + i4);
        nu2 o;
        o.x = pack2(v.x, v.y);
        o.y = pack2(v.z, v.w);
        *((nu2*)xb + i4) = o;
    }
    grid.sync();

    // ---- P1: histogram ----
    for (int e = gtid; e < NE; e += CSR_TH)
        atomicAdd(&cnt[__builtin_nontemporal_load(dst + e)], 1);
    grid.sync();

    // ---- P2a: per-chunk scan ----
    __shared__ int tmp[CSR_T];
    __shared__ int s_off;
    if (b < NB) {
        const int gid = b * CSR_T + tid;
        int v = (gid < NN) ? cnt[gid] : 0;
        tmp[tid] = v;
        __syncthreads();
        for (int off = 1; off < CSR_T; off <<= 1) {
            int t = (tid >= off) ? tmp[tid - off] : 0;
            __syncthreads();
            tmp[tid] += t;
            __syncthreads();
        }
        if (gid < NN) {
            pre[gid] = tmp[tid] - v;
            dinv[gid] = 1.0f / fmaxf((float)v, 1.0f);
        }
        if (tid == CSR_T - 1) bsum[b] = tmp[tid];
    }
    grid.sync();

    // ---- P2b: chunk offsets -> rp + padded cursor ----
    if (b < NB) {
        if (tid < 64) {
            int orig = (tid < NB) ? bsum[tid] : 0;
            int v = orig;
            for (int off = 1; off < 64; off <<= 1) {
                int t = __shfl_up(v, off);
                if (tid >= off) v += t;
            }
            if (tid == b) s_off = v - orig;
        }
        __syncthreads();
        const int gid = b * CSR_T + tid;
        if (gid < NN) {
            int r = pre[gid] + s_off;
            rp[gid] = r;
            curp[(size_t)gid * 16] = r;
        }
        if (gid == 0) rp[NN] = NE;
    }
    grid.sync();

    // ---- P3: bucket (ILP-4) ----
    {
        int d0 = 0, d1 = 0, d2 = 0, d3 = 0;
        ni2 p0, p1, p2, p3;
        const int e0 = gtid, e1 = gtid + CSR_TH, e2 = gtid + 2 * CSR_TH, e3 = gtid + 3 * CSR_TH;
        const bool v1 = e1 < NE, v2 = e2 < NE, v3 = e3 < NE;
        // e0 always < NE? gtid in [0, 262144), NE=800000 -> yes.
        d0 = __builtin_nontemporal_load(dst + e0);
        p0.x = __builtin_nontemporal_load(src + e0);
        p0.y = __float_as_int(__builtin_nontemporal_load(ew + e0));
        if (v1) {
            d1 = __builtin_nontemporal_load(dst + e1);
            p1.x = __builtin_nontemporal_load(src + e1);
            p1.y = __float_as_int(__builtin_nontemporal_load(ew + e1));
        }
        if (v2) {
            d2 = __builtin_nontemporal_load(dst + e2);
            p2.x = __builtin_nontemporal_load(src + e2);
            p2.y = __float_as_int(__builtin_nontemporal_load(ew + e2));
        }
        if (v3) {
            d3 = __builtin_nontemporal_load(dst + e3);
            p3.x = __builtin_nontemporal_load(src + e3);
            p3.y = __float_as_int(__builtin_nontemporal_load(ew + e3));
        }
        int q0 = atomicAdd(&curp[(size_t)d0 * 16], 1);
        int q1 = v1 ? atomicAdd(&curp[(size_t)d1 * 16], 1) : 0;
        int q2 = v2 ? atomicAdd(&curp[(size_t)d2 * 16], 1) : 0;
        int q3 = v3 ? atomicAdd(&curp[(size_t)d3 * 16], 1) : 0;
        __builtin_nontemporal_store(p0, epk + q0);
        if (v1) __builtin_nontemporal_store(p1, epk + q1);
        if (v2) __builtin_nontemporal_store(p2, epk + q2);
        if (v3) __builtin_nontemporal_store(p3, epk + q3);
    }
}

// gather0: xb bf16 [NN][128] -> aggb bf16 [NN][128] (scaled by dinv).
// 1 wave/node; edge metadata batch-loaded (lane L holds epk[b+L]) + shfl.
__global__ __launch_bounds__(256) void k_gather0(const unsigned short* __restrict__ xb,
                                                 const int* __restrict__ rp,
                                                 const int2* __restrict__ epk,
                                                 const float* __restrict__ dinv,
                                                 unsigned short* __restrict__ aggb) {
    int wid = (blockIdx.x * 256 + threadIdx.x) >> 6;
    int lane = threadIdx.x & 63;
    if (wid >= NN) return;
    int beg = rp[wid], end = rp[wid + 1];
    float di = dinv[wid];
    float ax = 0.f, ay = 0.f;
    for (int b = beg; b < end; b += 64) {
        int n = min(end - b, 64);
        int2 pk = epk[b + min(lane, n - 1)];
        int j = 0;
        for (; j + 3 < n; j += 4) {
            int s0 = __shfl(pk.x, j + 0), s1 = __shfl(pk.x, j + 1);
            int s2 = __shfl(pk.x, j + 2), s3 = __shfl(pk.x, j + 3);
            unsigned u0 = *(const unsigned*)(xb + (size_t)s0 * 128 + lane * 2);
            unsigned u1 = *(const unsigned*)(xb + (size_t)s1 * 128 + lane * 2);
            unsigned u2 = *(const unsigned*)(xb + (size_t)s2 * 128 + lane * 2);
            unsigned u3 = *(const unsigned*)(xb + (size_t)s3 * 128 + lane * 2);
            float w0 = __int_as_float(__shfl(pk.y, j + 0));
            float w1 = __int_as_float(__shfl(pk.y, j + 1));
            float w2 = __int_as_float(__shfl(pk.y, j + 2));
            float w3 = __int_as_float(__shfl(pk.y, j + 3));
            ax += w0 * b2f((unsigned short)(u0 & 0xFFFF)) + w1 * b2f((unsigned short)(u1 & 0xFFFF))
                + w2 * b2f((unsigned short)(u2 & 0xFFFF)) + w3 * b2f((unsigned short)(u3 & 0xFFFF));
            ay += w0 * b2f((unsigned short)(u0 >> 16)) + w1 * b2f((unsigned short)(u1 >> 16))
                + w2 * b2f((unsigned short)(u2 >> 16)) + w3 * b2f((unsigned short)(u3 >> 16));
        }
        for (; j < n; ++j) {
            int s = __shfl(pk.x, j);
            float w = __int_as_float(__shfl(pk.y, j));
            unsigned u = *(const unsigned*)(xb + (size_t)s * 128 + lane * 2);
            ax += w * b2f((unsigned short)(u & 0xFFFF));
            ay += w * b2f((unsigned short)(u >> 16));
        }
    }
    __builtin_nontemporal_store(pack2(ax * di, ay * di),
                                (unsigned*)(aggb + (size_t)wid * 128 + lane * 2));
}

// gather1: h1 bf16 [NN][256] -> aggb bf16 [NN][256]. 1 wave/node, 4 ch/lane.
__global__ __launch_bounds__(256) void k_gather1(const unsigned short* __restrict__ h,
                                                 const int* __restrict__ rp,
                                                 const int2* __restrict__ epk,
                                                 const float* __restrict__ dinv,
                                                 unsigned short* __restrict__ aggb) {
    int wid = (blockIdx.x * 256 + threadIdx.x) >> 6;
    int lane = threadIdx.x & 63;
    if (wid >= NN) return;
    int beg = rp[wid], end = rp[wid + 1];
    float di = dinv[wid];
    float a0 = 0.f, a1 = 0.f, a2 = 0.f, a3 = 0.f;
    for (int b = beg; b < end; b += 64) {
        int n = min(end - b, 64);
        int2 pk = epk[b + min(lane, n - 1)];
        int j = 0;
        for (; j + 3 < n; j += 4) {
            int s0 = __shfl(pk.x, j + 0), s1 = __shfl(pk.x, j + 1);
            int s2 = __shfl(pk.x, j + 2), s3 = __shfl(pk.x, j + 3);
            uint2 u0 = *(const uint2*)(h + (size_t)s0 * 256 + lane * 4);
            uint2 u1 = *(const uint2*)(h + (size_t)s1 * 256 + lane * 4);
            uint2 u2 = *(const uint2*)(h + (size_t)s2 * 256 + lane * 4);
            uint2 u3 = *(const uint2*)(h + (size_t)s3 * 256 + lane * 4);
            float w0 = __int_as_float(__shfl(pk.y, j + 0));
            float w1 = __int_as_float(__shfl(pk.y, j + 1));
            float w2 = __int_as_float(__shfl(pk.y, j + 2));
            float w3 = __int_as_float(__shfl(pk.y, j + 3));
            a0 += w0 * b2f((unsigned short)(u0.x & 0xFFFF)) + w1 * b2f((unsigned short)(u1.x & 0xFFFF))
                + w2 * b2f((unsigned short)(u2.x & 0xFFFF)) + w3 * b2f((unsigned short)(u3.x & 0xFFFF));
            a1 += w0 * b2f((unsigned short)(u0.x >> 16)) + w1 * b2f((unsigned short)(u1.x >> 16))
                + w2 * b2f((unsigned short)(u2.x >> 16)) + w3 * b2f((unsigned short)(u3.x >> 16));
            a2 += w0 * b2f((unsigned short)(u0.y & 0xFFFF)) + w1 * b2f((unsigned short)(u1.y & 0xFFFF))
                + w2 * b2f((unsigned short)(u2.y & 0xFFFF)) + w3 * b2f((unsigned short)(u3.y & 0xFFFF));
            a3 += w0 * b2f((unsigned short)(u0.y >> 16)) + w1 * b2f((unsigned short)(u1.y >> 16))
                + w2 * b2f((unsigned short)(u2.y >> 16)) + w3 * b2f((unsigned short)(u3.y >> 16));
        }
        for (; j < n; ++j) {
            int s = __shfl(pk.x, j);
            float w = __int_as_float(__shfl(pk.y, j));
            uint2 u = *(const uint2*)(h + (size_t)s * 256 + lane * 4);
            a0 += w * b2f((unsigned short)(u.x & 0xFFFF));
            a1 += w * b2f((unsigned short)(u.x >> 16));
            a2 += w * b2f((unsigned short)(u.y & 0xFFFF));
            a3 += w * b2f((unsigned short)(u.y >> 16));
        }
    }
    nu2 o;
    o.x = pack2(a0 * di, a1 * di);
    o.y = pack2(a2 * di, a3 * di);
    __builtin_nontemporal_store(o, (nu2*)(aggb + (size_t)wid * 256 + lane * 4));
}

// MFMA GEMM: C[row, 0:256] = concat(Aagg[row,:], Aself[row,:]) @ Bt^T + bias.
// 128x128 tile per block, 4 waves (2x2), 4x4 MFMA 16x16x32 per wave. bf16 in.
template <int K0, bool OUT_F32, bool RELU>
__global__ __launch_bounds__(256) void k_mfma(const unsigned short* __restrict__ Aagg,
                                              const unsigned short* __restrict__ Aself,
                                              const unsigned short* __restrict__ Bt,
                                              const float* __restrict__ bias,
                                              void* __restrict__ outp) {
    __shared__ unsigned short As[128 * 32];
    __shared__ unsigned short Bs[128 * 32];
    const int tid = threadIdx.x;
    const int m0 = blockIdx.x * 128;
    const int n0 = blockIdx.y * 128;
    const int K = 2 * K0;
    const int lane = tid & 63;
    const int w = tid >> 6;
    const int wr = w >> 1, wc = w & 1;
    const int fr = lane & 15, fq = lane >> 4;
    const int srow = tid >> 2;
    const int schunk = (tid & 3) * 8;

    v4f acc[4][4];
#pragma unroll
    for (int mi = 0; mi < 4; ++mi)
#pragma unroll
        for (int ni = 0; ni < 4; ++ni)
            acc[mi][ni] = (v4f){0.f, 0.f, 0.f, 0.f};

    for (int k0 = 0; k0 < K; k0 += 32) {
        const int kk = k0 + schunk;
        const int r0 = m0 + srow, r1 = m0 + srow + 64;
        uint4 av0 = make_uint4(0, 0, 0, 0), av1 = make_uint4(0, 0, 0, 0);
        const unsigned short* Asrc = (kk < K0) ? Aagg : (Aself - K0);
        if (r0 < NN) av0 = *(const uint4*)(Asrc + (size_t)r0 * K0 + kk);
        if (r1 < NN) av1 = *(const uint4*)(Asrc + (size_t)r1 * K0 + kk);
        uint4 bv0 = *(const uint4*)(Bt + (size_t)(n0 + srow) * K + kk);
        uint4 bv1 = *(const uint4*)(Bt + (size_t)(n0 + srow + 64) * K + kk);

        __syncthreads();
        *(uint4*)(As + srow * 32 + schunk) = av0;
        *(uint4*)(As + (srow + 64) * 32 + schunk) = av1;
        *(uint4*)(Bs + srow * 32 + schunk) = bv0;
        *(uint4*)(Bs + (srow + 64) * 32 + schunk) = bv1;
        __syncthreads();

        v8bf a[4], b[4];
#pragma unroll
        for (int mi = 0; mi < 4; ++mi)
            a[mi] = *(const v8bf*)(As + (wr * 64 + mi * 16 + fr) * 32 + fq * 8);
#pragma unroll
        for (int ni = 0; ni < 4; ++ni)
            b[ni] = *(const v8bf*)(Bs + (wc * 64 + ni * 16 + fr) * 32 + fq * 8);
#pragma unroll
        for (int mi = 0; mi < 4; ++mi)
#pragma unroll
            for (int ni = 0; ni < 4; ++ni)
                acc[mi][ni] = __builtin_amdgcn_mfma_f32_16x16x32_bf16(a[mi], b[ni], acc[mi][ni], 0, 0, 0);
    }

#pragma unroll
    for (int mi = 0; mi < 4; ++mi) {
#pragma unroll
        for (int ni = 0; ni < 4; ++ni) {
            const int col = n0 + wc * 64 + ni * 16 + fr;
            const float bb = bias[col];
#pragma unroll
            for (int r = 0; r < 4; ++r) {
                const int row = m0 + wr * 64 + mi * 16 + fq * 4 + r;
                if (row < NN) {
                    float v = acc[mi][ni][r] + bb;
                    if (RELU) v = fmaxf(v, 0.f);
                    if (OUT_F32)
                        __builtin_nontemporal_store(v, &((float*)outp)[(size_t)row * 256 + col]);
                    else
                        ((unsigned short*)outp)[(size_t)row * 256 + col] = f2b(v);
                }
            }
        }
    }
}

extern "C" void kernel_launch(void* const* d_in, const int* in_sizes, int n_in,
                              void* d_out, int out_size, void* d_ws, size_t ws_size,
                              hipStream_t stream) {
    const float* x   = (const float*)d_in[0];
    const int*   ei  = (const int*)d_in[1];
    const float* ew  = (const float*)d_in[2];
    const float* Wl0 = (const float*)d_in[3];
    const float* Wr0 = (const float*)d_in[4];
    const float* b0  = (const float*)d_in[5];
    const float* Wl1 = (const float*)d_in[6];
    const float* Wr1 = (const float*)d_in[7];
    const float* b1  = (const float*)d_in[8];
    float* out = (float*)d_out;

    const int* src = ei;
    const int* dst = ei + NE;

    // ws layout (bytes), total ~58.6 MB (same as round 7):
    //   0        dinv  f32[50000]
    //   204800   cnt   int[50000]; bsum@cnt+50048
    //   409600   rp    int[50001]
    //   614400   epk   int2[800000]   [pre aliases head, dead before bucket phase]
    //   7014400  Bt0   bf16[256*256]
    //   7145472  Bt1   bf16[256*512]
    //   7407616  h1b   bf16[50000*256]
    //   33007616 aggb  bf16[50000*256]; layer0: agg=[NN][128] (first half),
    //            xb in 2nd half. curp (padded cursor, 3.2MB) aliases agg's
    //            first half during k_csr (dead once gather0 writes agg).
    char* ws = (char*)d_ws;
    float*          dinv = (float*)(ws + 0);
    int*            cnt  = (int*)(ws + 204800);
    int*            bsum = cnt + 50048;
    int*            rp   = (int*)(ws + 409600);
    int*            pre  = (int*)(ws + 614400);
    ni2*            epk  = (ni2*)(ws + 614400);
    unsigned short* Bt0  = (unsigned short*)(ws + 7014400);
    unsigned short* Bt1  = (unsigned short*)(ws + 7145472);
    unsigned short* h1b  = (unsigned short*)(ws + 7407616);
    unsigned short* aggb = (unsigned short*)(ws + 33007616);
    int*            curp = (int*)aggb;               // padded cursor, stride 16 ints
    unsigned short* xb   = aggb + (size_t)NN * 128;  // dead once gather1 runs

    void* args[] = {(void*)&x, (void*)&Wl0, (void*)&Wr0, (void*)&Wl1, (void*)&Wr1,
                    (void*)&src, (void*)&dst, (void*)&ew,
                    (void*)&cnt, (void*)&pre, (void*)&bsum, (void*)&rp, (void*)&curp,
                    (void*)&dinv, (void*)&epk, (void*)&Bt0, (void*)&Bt1, (void*)&xb};
    hipLaunchCooperativeKernel((void*)k_csr, dim3(CSR_B), dim3(CSR_T), args, 0, stream);

    dim3 g((NN + 127) / 128, 2);
    // layer 0
    k_gather0<<<(NN * 64 + 255) / 256, 256, 0, stream>>>(xb, rp, (const int2*)epk, dinv, aggb);
    k_mfma<128, false, true><<<g, 256, 0, stream>>>(aggb, xb, Bt0, b0, h1b);
    // layer 1
    k_gather1<<<(NN * 64 + 255) / 256, 256, 0, stream>>>(h1b, rp, (const int2*)epk, dinv, aggb);
    k_mfma<256, true, false><<<g, 256, 0, stream>>>(aggb, h1b, Bt1, b1, out);
}

// Round 9
// 333.263 us; speedup vs baseline: 1.4383x; 1.4383x over previous
//
#include <hip/hip_runtime.h>

// GraphSAGE 2-layer. N=50000, E=800000, 128 -> 256 -> 256.
// Round 9: revert round-8 coop kernel (regressed). Round-7 structure plus:
//  - hist stores each edge's rank (the atomicAdd return) -> bucket loses all
//    atomics (pos = rp[dst] + rank), pure ILP-4 load/store.
//  - prep+hist fused into one kernel (cnt zeroed via memsetAsync).
//  - scan1+scan3f fused: 49 co-resident blocks, atomic-flag chunk offsets.

#define NN 50000
#define NE 800000

typedef __bf16 v8bf __attribute__((ext_vector_type(8)));
typedef float v4f __attribute__((ext_vector_type(4)));
typedef float nf4 __attribute__((ext_vector_type(4)));
typedef unsigned nu2 __attribute__((ext_vector_type(2)));

__device__ __forceinline__ unsigned short f2b(float f) {
    unsigned u = __float_as_uint(f);
    return (unsigned short)((u + 0x7FFFu + ((u >> 16) & 1u)) >> 16);
}
__device__ __forceinline__ float b2f(unsigned short h) {
    return __uint_as_float(((unsigned)h) << 16);
}
__device__ __forceinline__ unsigned pack2(float a, float b) {
    return (unsigned)f2b(a) | ((unsigned)f2b(b) << 16);
}

// Fused prep + hist. Sections by blockIdx (256 threads each):
//   [0,256)            Bt0 cast
//   [256,768)          Bt1 cast
//   [768,7018)         x -> bf16 (1.6M float4)
//   [7018,10143)       hist: cnt[dst]++ and rank[e] = old count (3125*256 = NE)
#define PH_BT0 256
#define PH_BT1 512
#define PH_XB  6250
#define PH_HIST 3125
__global__ __launch_bounds__(256) void k_preph(const float* __restrict__ x,
                                               const float* __restrict__ Wl0,
                                               const float* __restrict__ Wr0,
                                               const float* __restrict__ Wl1,
                                               const float* __restrict__ Wr1,
                                               const int* __restrict__ dst,
                                               int* __restrict__ cnt,
                                               int* __restrict__ rank,
                                               unsigned short* __restrict__ Bt0,
                                               unsigned short* __restrict__ Bt1,
                                               unsigned short* __restrict__ xb) {
    int b = blockIdx.x;
    int tid = threadIdx.x;
    if (b < PH_BT0) {
        int idx = b * 256 + tid;                        // [0, 65536)
        int n = idx >> 8, k = idx & 255;
        float v = (k < 128) ? Wl0[(size_t)k * 256 + n] : Wr0[(size_t)(k - 128) * 256 + n];
        Bt0[idx] = f2b(v);
    } else if (b < PH_BT0 + PH_BT1) {
        int idx = (b - PH_BT0) * 256 + tid;             // [0, 131072)
        int n = idx >> 9, k = idx & 511;
        float v = (k < 256) ? Wl1[(size_t)k * 256 + n] : Wr1[(size_t)(k - 256) * 256 + n];
        Bt1[idx] = f2b(v);
    } else if (b < PH_BT0 + PH_BT1 + PH_XB) {
        int i4 = (b - PH_BT0 - PH_BT1) * 256 + tid;     // [0, 1.6M)
        nf4 v = __builtin_nontemporal_load((const nf4*)x + i4);
        nu2 o;
        o.x = pack2(v.x, v.y);
        o.y = pack2(v.z, v.w);
        *((nu2*)xb + i4) = o;
    } else {
        int e = (b - PH_BT0 - PH_BT1 - PH_XB) * 256 + tid;  // [0, NE) exactly
        int d = __builtin_nontemporal_load(dst + e);
        int pos = atomicAdd(&cnt[d], 1);
        __builtin_nontemporal_store(pos, rank + e);
    }
}

// Fused scan: 49 blocks x 1024. Per-block LDS scan; chunk sums published via
// atomicExch flags (value+1), thread 0 spin-accumulates earlier chunks.
// 49 blocks <= 256 CUs: all co-resident.
__global__ __launch_bounds__(1024) void k_scanf(const int* __restrict__ cnt,
                                                int* __restrict__ bsum,
                                                int* __restrict__ rp,
                                                float* __restrict__ dinv) {
    __shared__ int tmp[1024];
    __shared__ int s_off;
    const int b = blockIdx.x, tid = threadIdx.x;
    const int gid = b * 1024 + tid;
    int v = (gid < NN) ? cnt[gid] : 0;
    tmp[tid] = v;
    __syncthreads();
    for (int off = 1; off < 1024; off <<= 1) {
        int t = (tid >= off) ? tmp[tid - off] : 0;
        __syncthreads();
        tmp[tid] += t;
        __syncthreads();
    }
    if (tid == 1023) atomicExch(&bsum[b], tmp[1023] + 1);   // publish (nonzero)
    if (tid == 0) {
        int off = 0;
        for (int i = 0; i < b; ++i) {
            int val;
            while ((val = atomicAdd(&bsum[i], 0)) == 0) {}
            off += val - 1;
        }
        s_off = off;
    }
    __syncthreads();
    if (gid < NN) {
        rp[gid] = tmp[tid] - v + s_off;
        dinv[gid] = 1.0f / fmaxf((float)v, 1.0f);
    }
    if (gid == 0) rp[NN] = NE;
}

// Atomic-free bucket: pos = rp[dst] + rank. 4 edges/thread, ILP.
__global__ __launch_bounds__(256) void k_bucket(const int* __restrict__ src,
                                                const int* __restrict__ dst,
                                                const float* __restrict__ ew,
                                                const int* __restrict__ rank,
                                                const int* __restrict__ rp,
                                                int2* __restrict__ epk) {
    int base = blockIdx.x * 1024 + threadIdx.x;
#pragma unroll
    for (int i = 0; i < 4; ++i) {
        int e = base + i * 256;
        if (e < NE) {
            int d = __builtin_nontemporal_load(dst + e);
            int r = __builtin_nontemporal_load(rank + e);
            int s = __builtin_nontemporal_load(src + e);
            float w = __builtin_nontemporal_load(ew + e);
            epk[rp[d] + r] = make_int2(s, __float_as_int(w));
        }
    }
}

// gather0: xb bf16 [NN][128] -> aggb bf16 [NN][128] (scaled by dinv).
// 1 wave/node; edge metadata batch-loaded (lane L holds epk[b+L]) + shfl.
__global__ __launch_bounds__(256) void k_gather0(const unsigned short* __restrict__ xb,
                                                 const int* __restrict__ rp,
                                                 const int2* __restrict__ epk,
                                                 const float* __restrict__ dinv,
                                                 unsigned short* __restrict__ aggb) {
    int wid = (blockIdx.x * 256 + threadIdx.x) >> 6;
    int lane = threadIdx.x & 63;
    if (wid >= NN) return;
    int beg = rp[wid], end = rp[wid + 1];
    float di = dinv[wid];
    float ax = 0.f, ay = 0.f;
    for (int b = beg; b < end; b += 64) {
        int n = min(end - b, 64);
        int2 pk = epk[b + min(lane, n - 1)];
        int j = 0;
        for (; j + 3 < n; j += 4) {
            int s0 = __shfl(pk.x, j + 0), s1 = __shfl(pk.x, j + 1);
            int s2 = __shfl(pk.x, j + 2), s3 = __shfl(pk.x, j + 3);
            unsigned u0 = *(const unsigned*)(xb + (size_t)s0 * 128 + lane * 2);
            unsigned u1 = *(const unsigned*)(xb + (size_t)s1 * 128 + lane * 2);
            unsigned u2 = *(const unsigned*)(xb + (size_t)s2 * 128 + lane * 2);
            unsigned u3 = *(const unsigned*)(xb + (size_t)s3 * 128 + lane * 2);
            float w0 = __int_as_float(__shfl(pk.y, j + 0));
            float w1 = __int_as_float(__shfl(pk.y, j + 1));
            float w2 = __int_as_float(__shfl(pk.y, j + 2));
            float w3 = __int_as_float(__shfl(pk.y, j + 3));
            ax += w0 * b2f((unsigned short)(u0 & 0xFFFF)) + w1 * b2f((unsigned short)(u1 & 0xFFFF))
                + w2 * b2f((unsigned short)(u2 & 0xFFFF)) + w3 * b2f((unsigned short)(u3 & 0xFFFF));
            ay += w0 * b2f((unsigned short)(u0 >> 16)) + w1 * b2f((unsigned short)(u1 >> 16))
                + w2 * b2f((unsigned short)(u2 >> 16)) + w3 * b2f((unsigned short)(u3 >> 16));
        }
        for (; j < n; ++j) {
            int s = __shfl(pk.x, j);
            float w = __int_as_float(__shfl(pk.y, j));
            unsigned u = *(const unsigned*)(xb + (size_t)s * 128 + lane * 2);
            ax += w * b2f((unsigned short)(u & 0xFFFF));
            ay += w * b2f((unsigned short)(u >> 16));
        }
    }
    __builtin_nontemporal_store(pack2(ax * di, ay * di),
                                (unsigned*)(aggb + (size_t)wid * 128 + lane * 2));
}

// gather1: h1 bf16 [NN][256] -> aggb bf16 [NN][256]. 1 wave/node, 4 ch/lane.
__global__ __launch_bounds__(256) void k_gather1(const unsigned short* __restrict__ h,
                                                 const int* __restrict__ rp,
                                                 const int2* __restrict__ epk,
                                                 const float* __restrict__ dinv,
                                                 unsigned short* __restrict__ aggb) {
    int wid = (blockIdx.x * 256 + threadIdx.x) >> 6;
    int lane = threadIdx.x & 63;
    if (wid >= NN) return;
    int beg = rp[wid], end = rp[wid + 1];
    float di = dinv[wid];
    float a0 = 0.f, a1 = 0.f, a2 = 0.f, a3 = 0.f;
    for (int b = beg; b < end; b += 64) {
        int n = min(end - b, 64);
        int2 pk = epk[b + min(lane, n - 1)];
        int j = 0;
        for (; j + 3 < n; j += 4) {
            int s0 = __shfl(pk.x, j + 0), s1 = __shfl(pk.x, j + 1);
            int s2 = __shfl(pk.x, j + 2), s3 = __shfl(pk.x, j + 3);
            uint2 u0 = *(const uint2*)(h + (size_t)s0 * 256 + lane * 4);
            uint2 u1 = *(const uint2*)(h + (size_t)s1 * 256 + lane * 4);
            uint2 u2 = *(const uint2*)(h + (size_t)s2 * 256 + lane * 4);
            uint2 u3 = *(const uint2*)(h + (size_t)s3 * 256 + lane * 4);
            float w0 = __int_as_float(__shfl(pk.y, j + 0));
            float w1 = __int_as_float(__shfl(pk.y, j + 1));
            float w2 = __int_as_float(__shfl(pk.y, j + 2));
            float w3 = __int_as_float(__shfl(pk.y, j + 3));
            a0 += w0 * b2f((unsigned short)(u0.x & 0xFFFF)) + w1 * b2f((unsigned short)(u1.x & 0xFFFF))
                + w2 * b2f((unsigned short)(u2.x & 0xFFFF)) + w3 * b2f((unsigned short)(u3.x & 0xFFFF));
            a1 += w0 * b2f((unsigned short)(u0.x >> 16)) + w1 * b2f((unsigned short)(u1.x >> 16))
                + w2 * b2f((unsigned short)(u2.x >> 16)) + w3 * b2f((unsigned short)(u3.x >> 16));
            a2 += w0 * b2f((unsigned short)(u0.y & 0xFFFF)) + w1 * b2f((unsigned short)(u1.y & 0xFFFF))
                + w2 * b2f((unsigned short)(u2.y & 0xFFFF)) + w3 * b2f((unsigned short)(u3.y & 0xFFFF));
            a3 += w0 * b2f((unsigned short)(u0.y >> 16)) + w1 * b2f((unsigned short)(u1.y >> 16))
                + w2 * b2f((unsigned short)(u2.y >> 16)) + w3 * b2f((unsigned short)(u3.y >> 16));
        }
        for (; j < n; ++j) {
            int s = __shfl(pk.x, j);
            float w = __int_as_float(__shfl(pk.y, j));
            uint2 u = *(const uint2*)(h + (size_t)s * 256 + lane * 4);
            a0 += w * b2f((unsigned short)(u.x & 0xFFFF));
            a1 += w * b2f((unsigned short)(u.x >> 16));
            a2 += w * b2f((unsigned short)(u.y & 0xFFFF));
            a3 += w * b2f((unsigned short)(u.y >> 16));
        }
    }
    nu2 o;
    o.x = pack2(a0 * di, a1 * di);
    o.y = pack2(a2 * di, a3 * di);
    __builtin_nontemporal_store(o, (nu2*)(aggb + (size_t)wid * 256 + lane * 4));
}

// MFMA GEMM: C[row, 0:256] = concat(Aagg[row,:], Aself[row,:]) @ Bt^T + bias.
// 128x128 tile per block, 4 waves (2x2), 4x4 MFMA 16x16x32 per wave. bf16 in.
template <int K0, bool OUT_F32, bool RELU>
__global__ __launch_bounds__(256) void k_mfma(const unsigned short* __restrict__ Aagg,
                                              const unsigned short* __restrict__ Aself,
                                              const unsigned short* __restrict__ Bt,
                                              const float* __restrict__ bias,
                                              void* __restrict__ outp) {
    __shared__ unsigned short As[128 * 32];
    __shared__ unsigned short Bs[128 * 32];
    const int tid = threadIdx.x;
    const int m0 = blockIdx.x * 128;
    const int n0 = blockIdx.y * 128;
    const int K = 2 * K0;
    const int lane = tid & 63;
    const int w = tid >> 6;
    const int wr = w >> 1, wc = w & 1;
    const int fr = lane & 15, fq = lane >> 4;
    const int srow = tid >> 2;
    const int schunk = (tid & 3) * 8;

    v4f acc[4][4];
#pragma unroll
    for (int mi = 0; mi < 4; ++mi)
#pragma unroll
        for (int ni = 0; ni < 4; ++ni)
            acc[mi][ni] = (v4f){0.f, 0.f, 0.f, 0.f};

    for (int k0 = 0; k0 < K; k0 += 32) {
        const int kk = k0 + schunk;
        const int r0 = m0 + srow, r1 = m0 + srow + 64;
        uint4 av0 = make_uint4(0, 0, 0, 0), av1 = make_uint4(0, 0, 0, 0);
        const unsigned short* Asrc = (kk < K0) ? Aagg : (Aself - K0);
        if (r0 < NN) av0 = *(const uint4*)(Asrc + (size_t)r0 * K0 + kk);
        if (r1 < NN) av1 = *(const uint4*)(Asrc + (size_t)r1 * K0 + kk);
        uint4 bv0 = *(const uint4*)(Bt + (size_t)(n0 + srow) * K + kk);
        uint4 bv1 = *(const uint4*)(Bt + (size_t)(n0 + srow + 64) * K + kk);

        __syncthreads();
        *(uint4*)(As + srow * 32 + schunk) = av0;
        *(uint4*)(As + (srow + 64) * 32 + schunk) = av1;
        *(uint4*)(Bs + srow * 32 + schunk) = bv0;
        *(uint4*)(Bs + (srow + 64) * 32 + schunk) = bv1;
        __syncthreads();

        v8bf a[4], b[4];
#pragma unroll
        for (int mi = 0; mi < 4; ++mi)
            a[mi] = *(const v8bf*)(As + (wr * 64 + mi * 16 + fr) * 32 + fq * 8);
#pragma unroll
        for (int ni = 0; ni < 4; ++ni)
            b[ni] = *(const v8bf*)(Bs + (wc * 64 + ni * 16 + fr) * 32 + fq * 8);
#pragma unroll
        for (int mi = 0; mi < 4; ++mi)
#pragma unroll
            for (int ni = 0; ni < 4; ++ni)
                acc[mi][ni] = __builtin_amdgcn_mfma_f32_16x16x32_bf16(a[mi], b[ni], acc[mi][ni], 0, 0, 0);
    }

#pragma unroll
    for (int mi = 0; mi < 4; ++mi) {
#pragma unroll
        for (int ni = 0; ni < 4; ++ni) {
            const int col = n0 + wc * 64 + ni * 16 + fr;
            const float bb = bias[col];
#pragma unroll
            for (int r = 0; r < 4; ++r) {
                const int row = m0 + wr * 64 + mi * 16 + fq * 4 + r;
                if (row < NN) {
                    float v = acc[mi][ni][r] + bb;
                    if (RELU) v = fmaxf(v, 0.f);
                    if (OUT_F32)
                        __builtin_nontemporal_store(v, &((float*)outp)[(size_t)row * 256 + col]);
                    else
                        ((unsigned short*)outp)[(size_t)row * 256 + col] = f2b(v);
                }
            }
        }
    }
}

extern "C" void kernel_launch(void* const* d_in, const int* in_sizes, int n_in,
                              void* d_out, int out_size, void* d_ws, size_t ws_size,
                              hipStream_t stream) {
    const float* x   = (const float*)d_in[0];
    const int*   ei  = (const int*)d_in[1];
    const float* ew  = (const float*)d_in[2];
    const float* Wl0 = (const float*)d_in[3];
    const float* Wr0 = (const float*)d_in[4];
    const float* b0  = (const float*)d_in[5];
    const float* Wl1 = (const float*)d_in[6];
    const float* Wr1 = (const float*)d_in[7];
    const float* b1  = (const float*)d_in[8];
    float* out = (float*)d_out;

    const int* src = ei;
    const int* dst = ei + NE;

    // ws layout (bytes), total ~58.6 MB (same as round 7):
    //   0        dinv  f32[50000]
    //   204800   cnt   int[50000]; bsum @ cnt+50048 (both zeroed by one memset)
    //   409600   rp    int[50001]
    //   614400   epk   int2[800000]
    //   7014400  Bt0   bf16[256*256]
    //   7145472  Bt1   bf16[256*512]
    //   7407616  h1b   bf16[50000*256]; rank int[800000] aliases head (dead
    //            after bucket, before mfma0 writes h1b)
    //   33007616 aggb  bf16[50000*256]; layer0: agg=[NN][128], xb in 2nd half
    char* ws = (char*)d_ws;
    float*          dinv = (float*)(ws + 0);
    int*            cnt  = (int*)(ws + 204800);
    int*            bsum = cnt + 50048;
    int*            rp   = (int*)(ws + 409600);
    int2*           epk  = (int2*)(ws + 614400);
    unsigned short* Bt0  = (unsigned short*)(ws + 7014400);
    unsigned short* Bt1  = (unsigned short*)(ws + 7145472);
    unsigned short* h1b  = (unsigned short*)(ws + 7407616);
    int*            rank = (int*)h1b;
    unsigned short* aggb = (unsigned short*)(ws + 33007616);
    unsigned short* xb   = aggb + (size_t)NN * 128;

    hipMemsetAsync(cnt, 0, 204800, stream);  // zeros cnt + bsum
    k_preph<<<PH_BT0 + PH_BT1 + PH_XB + PH_HIST, 256, 0, stream>>>(
        x, Wl0, Wr0, Wl1, Wr1, dst, cnt, rank, Bt0, Bt1, xb);
    k_scanf<<<49, 1024, 0, stream>>>(cnt, bsum, rp, dinv);
    k_bucket<<<(NE + 1023) / 1024, 256, 0, stream>>>(src, dst, ew, rank, rp, epk);

    dim3 g((NN + 127) / 128, 2);
    // layer 0
    k_gather0<<<(NN * 64 + 255) / 256, 256, 0, stream>>>(xb, rp, (const int2*)epk, dinv, aggb);
    k_mfma<128, false, true><<<g, 256, 0, stream>>>(aggb, xb, Bt0, b0, h1b);
    // layer 1
    k_gather1<<<(NN * 64 + 255) / 256, 256, 0, stream>>>(h1b, rp, (const int2*)epk, dinv, aggb);
    k_mfma<256, true, false><<<g, 256, 0, stream>>>(aggb, h1b, Bt1, b1, out);
}